// Round 9
// baseline (17.983 us; speedup 1.0000x reference)
//
#include <hip/hip_runtime.h>
#include <math.h>

// B = 16384 independent 6-var / 9-constraint QPs, 8 IPM iterations.
// f64 (range safety), rcp+Newton for divides, 3x3 Schur/adjugate direction.
// ROUND 9: 2 QPs PER THREAD, unroll-and-jam. We are latency-bound (~40%
// active-SIMD issue occupancy, stall ~2.5x) at 1 wave/SIMD with 75% of SIMDs
// idle by grid size. Two independent IPM chains interleaved in one basic
// block let the second chain's issue slots hide under the first's stalls:
// predicted ~2x. Per-QP arithmetic is BIT-IDENTICAL to round 8 (11.77us,
// absmax 0.03125): body verbatim, called twice per loop iteration.
//
// Qmod nonzeros: [0][0]=4.001 [0][1]=-4 [1][0]=-4 [1][1]=4.001, diag 2..5 = 0.001
// R rows 0..5 = -e_i ; rows 6..8 = a_j:
//   a0 = [-1, 1,-1, 1, 0, 0]
//   a1 = [ 1,-1,-1, 0, 1, 0]
//   a2 = [ 1, 1, 0, 0, 0, 1]

#define N_IT 8

__device__ __forceinline__ double drcp1(double x) {   // ~full f64 after 1 Newton
    double r = __builtin_amdgcn_rcp(x);
    double e = fma(-x, r, 1.0);
    return fma(r, e, r);
}

__device__ __forceinline__ void ipm_iter(double* __restrict__ z,
                                         double* __restrict__ s,
                                         double* __restrict__ lam,
                                         double p0, double p1, double p2,
                                         double h6, double h7, double h8) {
    // ---- Qz + p ----
    double Qp0 = 4.001 * z[0] - 4.0 * z[1] + p0;
    double Qp1 = -4.0 * z[0] + 4.001 * z[1] + p1;
    double Qp2 = 0.001 * z[2] + p2;
    double Qp3 = 0.001 * z[3] + 1.0;
    double Qp4 = 0.001 * z[4] + 1.0;
    double Qp5 = 0.001 * z[5] + 1.0;

    // Rz - h
    double rzh[9];
    rzh[0] = -z[0]; rzh[1] = -z[1]; rzh[2] = -z[2];
    rzh[3] = -z[3]; rzh[4] = -z[4]; rzh[5] = -z[5];
    rzh[6] = -z[0] + z[1] - z[2] + z[3] - h6;
    rzh[7] =  z[0] - z[1] - z[2] + z[4] - h7;
    rzh[8] =  z[0] + z[1] + z[5] - h8;

    // ---- barrier parameter (tree-summed dot) ----
    double sl0 = s[0] * lam[0], sl1 = s[1] * lam[1], sl2 = s[2] * lam[2];
    double sl3 = s[3] * lam[3], sl4 = s[4] * lam[4], sl5 = s[5] * lam[5];
    double sl6 = s[6] * lam[6], sl7 = s[7] * lam[7], sl8 = s[8] * lam[8];
    double dA = (sl0 + sl1) + (sl2 + sl3);
    double dB = (sl4 + sl5) + (sl6 + sl7);
    double mip = (0.1 / 9.0) * ((dA + dB) + sl8);

    // ---- invs, invl, W, g, u (independent rcp chains) ----
    double invs[9], invl[9], W[9], g[9], u[9];
#pragma unroll
    for (int k = 0; k < 9; ++k) {
        invs[k] = drcp1(s[k]);
        invl[k] = drcp1(lam[k]);
        W[k]    = lam[k] * invs[k];
        g[k]    = fma(mip, invl[k], rzh[k]);   // rp + mip/lam - s (s cancels)
        u[k]    = fma(W[k], g[k], lam[k]);     // lam + W*g
    }
    double w6 = W[6], w7 = W[7], w8 = W[8];

    // rhs = -(Qz+p) - R^T u
    double rhs0 = -Qp0 + u[0] + u[6] - u[7] - u[8];
    double rhs1 = -Qp1 + u[1] - u[6] + u[7] - u[8];
    double rhs2 = -Qp2 + u[2] + u[6] + u[7];
    double rhs3 = -Qp3 + u[3] - u[6];
    double rhs4 = -Qp4 + u[4] - u[7];
    double rhs5 = -Qp5 + u[5] - u[8];

    // ---- eliminate z3..z5 ----
    double dp3 = 0.001 + W[3], dp4 = 0.001 + W[4], dp5 = 0.001 + W[5];
    double d3 = dp3 + w6, d4 = dp4 + w7, d5 = dp5 + w8;
    double id3 = drcp1(d3), id4 = drcp1(d4), id5 = drcp1(d5);
    double e6 = w6 * id3, e7 = w7 * id4, e8 = w8 * id5;
    double c6 = w6 * dp3 * id3;
    double c7 = w7 * dp4 * id4;
    double c8 = w8 * dp5 * id5;
    double q6 = e6 * rhs3, q7 = e7 * rhs4, q8 = e8 * rhs5;

    double r0 = rhs0 + q6 - q7 - q8;
    double r1 = rhs1 - q6 + q7 - q8;
    double r2 = rhs2 + q6 + q7;

    double csum = c6 + c7 + c8;
    double S00 = 4.001 + W[0] + csum;
    double S01 = -4.0 - c6 - c7 + c8;
    double S02 = c6 - c7;
    double S11 = 4.001 + W[1] + csum;
    double S12 = -c6 + c7;
    double S22 = 0.001 + W[2] + c6 + c7;

    // ---- 3x3 symmetric solve by adjugate ----
    double c00 = fma(S11, S22, -S12 * S12);
    double c01 = fma(S02, S12, -S01 * S22);
    double c02 = fma(S01, S12, -S02 * S11);
    double c11 = fma(S00, S22, -S02 * S02);
    double c12 = fma(S01, S02, -S00 * S12);
    double c22 = fma(S00, S11, -S01 * S01);
    double det = fma(S00, c00, fma(S01, c01, S02 * c02));
    det = fmax(det, 1e-280);
    double idet = drcp1(det);
    double x0 = fma(c00, r0, fma(c01, r1, c02 * r2)) * idet;
    double x1 = fma(c01, r0, fma(c11, r1, c12 * r2)) * idet;
    double x2 = fma(c02, r0, fma(c12, r1, c22 * r2)) * idet;

    double a6x = -x0 + x1 - x2;
    double a7x =  x0 - x1 - x2;
    double a8x =  x0 + x1;
    double dz3 = fma(-e6, a6x, rhs3 * id3);
    double dz4 = fma(-e7, a7x, rhs4 * id4);
    double dz5 = fma(-e8, a8x, rhs5 * id5);

    // ---- dlam, ds ----
    double Rdz[9];
    Rdz[0] = -x0; Rdz[1] = -x1; Rdz[2] = -x2;
    Rdz[3] = -dz3; Rdz[4] = -dz4; Rdz[5] = -dz5;
    Rdz[6] = a6x + dz3;
    Rdz[7] = a7x + dz4;
    Rdz[8] = a8x + dz5;

    double dl[9], ds[9];
#pragma unroll
    for (int k = 0; k < 9; ++k) {
        dl[k] = W[k] * (Rdz[k] + g[k]);
        double comp = fma(-s[k], lam[k], mip);
        ds[k] = fma(-s[k], dl[k], comp) * invl[k];
    }

    // ---- step length ----
    double m0 = fmax(-ds[0] * invs[0], -dl[0] * invl[0]);
    double m1 = fmax(-ds[1] * invs[1], -dl[1] * invl[1]);
    double m2 = fmax(-ds[2] * invs[2], -dl[2] * invl[2]);
    double m3 = fmax(-ds[3] * invs[3], -dl[3] * invl[3]);
    double m4 = fmax(-ds[4] * invs[4], -dl[4] * invl[4]);
    double m5 = fmax(-ds[5] * invs[5], -dl[5] * invl[5]);
    double m6 = fmax(-ds[6] * invs[6], -dl[6] * invl[6]);
    double m7 = fmax(-ds[7] * invs[7], -dl[7] * invl[7]);
    double m8 = fmax(-ds[8] * invs[8], -dl[8] * invl[8]);
    double MA = fmax(fmax(m0, m1), fmax(m2, m3));
    double MB = fmax(fmax(m4, m5), fmax(m6, m7));
    double M  = fmax(fmax(MA, MB), fmax(m8, 1e-300));
    double alpha = 0.99 * fmin(1.0, __builtin_amdgcn_rcp(M));

    z[0] = fma(alpha, x0, z[0]);
    z[1] = fma(alpha, x1, z[1]);
    z[2] = fma(alpha, x2, z[2]);
    z[3] = fma(alpha, dz3, z[3]);
    z[4] = fma(alpha, dz4, z[4]);
    z[5] = fma(alpha, dz5, z[5]);
#pragma unroll
    for (int k = 0; k < 9; ++k) {
        s[k]   = fma(alpha, ds[k], s[k]);
        lam[k] = fma(alpha, dl[k], lam[k]);
    }
}

__device__ __forceinline__ double qp_cost(const double* __restrict__ z,
                                          double p0, double p1, double p2,
                                          double beta) {
    double zQz = 4.001 * (z[0] * z[0] + z[1] * z[1]) - 8.0 * z[0] * z[1]
               + 0.001 * (z[2] * z[2] + z[3] * z[3] + z[4] * z[4] + z[5] * z[5]);
    double pz = p0 * z[0] + p1 * z[1] + p2 * z[2] + z[3] + z[4] + z[5];
    return 0.5 * zQz + pz + beta * beta;
}

__global__ __launch_bounds__(64, 1) void qp_kernel(const float* __restrict__ vk,
                                                   const float* __restrict__ mup,
                                                   float* __restrict__ out, int half) {
    int i = blockIdx.x * blockDim.x + threadIdx.x;
    if (i >= half) return;

    const double mu = (double)mup[0];

    // ---- QP A: element i ----
    const double vA = (double)vk[i];
    const double betaA = -vA;
    double pA0 = 3.0 * vA + 2.0, pA1 = -pA0, pA2 = mu;
    double hA6 = vA + 2.0, hA7 = -hA6, hA8 = mu;
    double zA[6] = {0,0,0,0,0,0};
    double sA[9], lamA[9];

    // ---- QP B: element i + half ----
    const double vB = (double)vk[i + half];
    const double betaB = -vB;
    double pB0 = 3.0 * vB + 2.0, pB1 = -pB0, pB2 = mu;
    double hB6 = vB + 2.0, hB7 = -hB6, hB8 = mu;
    double zB[6] = {0,0,0,0,0,0};
    double sB[9], lamB[9];

#pragma unroll
    for (int k = 0; k < 9; ++k) { sA[k] = 1.0; lamA[k] = 1.0; sB[k] = 1.0; lamB[k] = 1.0; }

    for (int it = 0; it < N_IT; ++it) {
        ipm_iter(zA, sA, lamA, pA0, pA1, pA2, hA6, hA7, hA8);
        ipm_iter(zB, sB, lamB, pB0, pB1, pB2, hB6, hB7, hB8);
    }

    out[i]        = (float)qp_cost(zA, pA0, pA1, pA2, betaA);
    out[i + half] = (float)qp_cost(zB, pB0, pB1, pB2, betaB);
}

extern "C" void kernel_launch(void* const* d_in, const int* in_sizes, int n_in,
                              void* d_out, int out_size, void* d_ws, size_t ws_size,
                              hipStream_t stream) {
    const float* vk = (const float*)d_in[0];
    const float* mu = (const float*)d_in[1];
    float* out = (float*)d_out;
    int B = in_sizes[0];
    int half = B / 2;
    int block = 64;
    int grid = (half + block - 1) / block;
    hipLaunchKernelGGL(qp_kernel, dim3(grid), dim3(block), 0, stream, vk, mu, out, half);
}

// Round 10
// 11.544 us; speedup vs baseline: 1.5578x; 1.5578x over previous
//
#include <hip/hip_runtime.h>
#include <math.h>

// B = 16384 independent 6-var / 9-constraint QPs, 8 IPM iterations.
// Per-thread, fully unrolled, f64, 3x3 Schur/adjugate direction.
// ROUND 10 = ROUND 8 (11.77us, absmax 0.03125) with Newton steps stripped
// from all rcps except idet. Rationale: the IPM fixed point is set by the
// residuals (rcp-free); rcps only shape the Newton DIRECTION -> inexact-
// Jacobian Newton converges to the same solution. Raw v_rcp_f64 for
// invs/invl/id3..5 removes ~44 dependent f64 FMAs/iter and shortens the
// 3 serial rcp stages on the critical path.
// Round-9 lesson (2 QPs/thread, 17.98us): ILP-jam trades waves 1:1 for ILP
// and the scheduler only achieved 1.24x overlap under register pressure.
//
// Qmod nonzeros: [0][0]=4.001 [0][1]=-4 [1][0]=-4 [1][1]=4.001, diag 2..5 = 0.001
// R rows 0..5 = -e_i ; rows 6..8 = a_j:
//   a0 = [-1, 1,-1, 1, 0, 0]
//   a1 = [ 1,-1,-1, 0, 1, 0]
//   a2 = [ 1, 1, 0, 0, 0, 1]

#define N_IT 8

__device__ __forceinline__ double drcp1(double x) {   // 1 Newton step
    double r = __builtin_amdgcn_rcp(x);
    double e = fma(-x, r, 1.0);
    return fma(r, e, r);
}

__global__ __launch_bounds__(64, 1) void qp_kernel(const float* __restrict__ vk,
                                                   const float* __restrict__ mup,
                                                   float* __restrict__ out, int B) {
    int i = blockIdx.x * blockDim.x + threadIdx.x;
    if (i >= B) return;

    const double v  = (double)vk[i];
    const double mu = (double)mup[0];
    const double beta = -v;
    const double vu = v + 2.0;

    // p = [3v+2, -(3v+2), mu, 1, 1, 1]
    double p0 = 3.0 * v + 2.0;
    double p1 = -p0;
    double p2 = mu;
    // h = [0 x6, vu, -vu, mu]
    double h6 = vu, h7 = -vu, h8 = mu;

    double z[6] = {0.0, 0.0, 0.0, 0.0, 0.0, 0.0};
    double s[9], lam[9];
#pragma unroll
    for (int k = 0; k < 9; ++k) { s[k] = 1.0; lam[k] = 1.0; }

    for (int it = 0; it < N_IT; ++it) {
        // ---- Qz + p ----
        double Qp0 = 4.001 * z[0] - 4.0 * z[1] + p0;
        double Qp1 = -4.0 * z[0] + 4.001 * z[1] + p1;
        double Qp2 = 0.001 * z[2] + p2;
        double Qp3 = 0.001 * z[3] + 1.0;
        double Qp4 = 0.001 * z[4] + 1.0;
        double Qp5 = 0.001 * z[5] + 1.0;

        // Rz - h  (rows 0..5: -z_k; rows 6..8: a_j z - h_j)
        double rzh[9];
        rzh[0] = -z[0]; rzh[1] = -z[1]; rzh[2] = -z[2];
        rzh[3] = -z[3]; rzh[4] = -z[4]; rzh[5] = -z[5];
        rzh[6] = -z[0] + z[1] - z[2] + z[3] - h6;
        rzh[7] =  z[0] - z[1] - z[2] + z[4] - h7;
        rzh[8] =  z[0] + z[1] + z[5] - h8;

        // ---- barrier parameter (tree-summed dot) ----
        double sl0 = s[0] * lam[0], sl1 = s[1] * lam[1], sl2 = s[2] * lam[2];
        double sl3 = s[3] * lam[3], sl4 = s[4] * lam[4], sl5 = s[5] * lam[5];
        double sl6 = s[6] * lam[6], sl7 = s[7] * lam[7], sl8 = s[8] * lam[8];
        double dA = (sl0 + sl1) + (sl2 + sl3);
        double dB = (sl4 + sl5) + (sl6 + sl7);
        double mip = (0.1 / 9.0) * ((dA + dB) + sl8);

        // ---- invs, invl, W, g, u (raw v_rcp_f64: inexact-Jacobian Newton) ----
        double invs[9], invl[9], W[9], g[9], u[9];
#pragma unroll
        for (int k = 0; k < 9; ++k) {
            invs[k] = __builtin_amdgcn_rcp(s[k]);
            invl[k] = __builtin_amdgcn_rcp(lam[k]);
            W[k]    = lam[k] * invs[k];
            g[k]    = fma(mip, invl[k], rzh[k]);   // rp + mip/lam - s (s cancels)
            u[k]    = fma(W[k], g[k], lam[k]);     // lam + W*g
        }
        double w6 = W[6], w7 = W[7], w8 = W[8];

        // rhs = -(Qz+p) - R^T u ; (R^T u)_k = -u_k + sum_j a_j[k] u_{6+j}
        double rhs0 = -Qp0 + u[0] + u[6] - u[7] - u[8];
        double rhs1 = -Qp1 + u[1] - u[6] + u[7] - u[8];
        double rhs2 = -Qp2 + u[2] + u[6] + u[7];
        double rhs3 = -Qp3 + u[3] - u[6];
        double rhs4 = -Qp4 + u[4] - u[7];
        double rhs5 = -Qp5 + u[5] - u[8];

        // ---- eliminate z3..z5 (diagonal block): d_j = 0.001+W[3+j]+w_j ----
        double dp3 = 0.001 + W[3], dp4 = 0.001 + W[4], dp5 = 0.001 + W[5];
        double d3 = dp3 + w6, d4 = dp4 + w7, d5 = dp5 + w8;
        double id3 = __builtin_amdgcn_rcp(d3);
        double id4 = __builtin_amdgcn_rcp(d4);
        double id5 = __builtin_amdgcn_rcp(d5);
        double e6 = w6 * id3, e7 = w7 * id4, e8 = w8 * id5;   // w_j/d_j
        double c6 = w6 * dp3 * id3;   // hat-c_j = w_j dp_j / d_j (all-positive)
        double c7 = w7 * dp4 * id4;
        double c8 = w8 * dp5 * id5;
        double q6 = e6 * rhs3, q7 = e7 * rhs4, q8 = e8 * rhs5;

        // reduced rhs (3): rhs012 - sum_j q_j a'_j
        double r0 = rhs0 + q6 - q7 - q8;
        double r1 = rhs1 - q6 + q7 - q8;
        double r2 = rhs2 + q6 + q7;

        // reduced matrix S = Q3 + diag(W0..2) + sum_j c_j a'_j a'_j^T
        double csum = c6 + c7 + c8;
        double S00 = 4.001 + W[0] + csum;
        double S01 = -4.0 - c6 - c7 + c8;
        double S02 = c6 - c7;
        double S11 = 4.001 + W[1] + csum;
        double S12 = -c6 + c7;
        double S22 = 0.001 + W[2] + c6 + c7;

        // ---- 3x3 symmetric solve by adjugate (1 rcp+Newton, max ILP) ----
        double c00 = fma(S11, S22, -S12 * S12);
        double c01 = fma(S02, S12, -S01 * S22);
        double c02 = fma(S01, S12, -S02 * S11);
        double c11 = fma(S00, S22, -S02 * S02);
        double c12 = fma(S01, S02, -S00 * S12);
        double c22 = fma(S00, S11, -S01 * S01);
        double det = fma(S00, c00, fma(S01, c01, S02 * c02));
        det = fmax(det, 1e-280);      // S is SPD; guard vs rounding
        double idet = drcp1(det);
        double x0 = fma(c00, r0, fma(c01, r1, c02 * r2)) * idet;
        double x1 = fma(c01, r0, fma(c11, r1, c12 * r2)) * idet;
        double x2 = fma(c02, r0, fma(c12, r1, c22 * r2)) * idet;

        // back-substitute z3..z5
        double a6x = -x0 + x1 - x2;
        double a7x =  x0 - x1 - x2;
        double a8x =  x0 + x1;
        double dz3 = fma(-e6, a6x, rhs3 * id3);
        double dz4 = fma(-e7, a7x, rhs4 * id4);
        double dz5 = fma(-e8, a8x, rhs5 * id5);

        // ---- dlam, ds ----
        double Rdz[9];
        Rdz[0] = -x0; Rdz[1] = -x1; Rdz[2] = -x2;
        Rdz[3] = -dz3; Rdz[4] = -dz4; Rdz[5] = -dz5;
        Rdz[6] = a6x + dz3;
        Rdz[7] = a7x + dz4;
        Rdz[8] = a8x + dz5;

        double dl[9], ds[9];
#pragma unroll
        for (int k = 0; k < 9; ++k) {
            dl[k] = W[k] * (Rdz[k] + g[k]);
            double comp = fma(-s[k], lam[k], mip);
            ds[k] = fma(-s[k], dl[k], comp) * invl[k];
        }

        // ---- step length: alpha = 0.99*min(1, 1/max_k(-dx_k*inv_x_k)) ----
        double m0 = fmax(-ds[0] * invs[0], -dl[0] * invl[0]);
        double m1 = fmax(-ds[1] * invs[1], -dl[1] * invl[1]);
        double m2 = fmax(-ds[2] * invs[2], -dl[2] * invl[2]);
        double m3 = fmax(-ds[3] * invs[3], -dl[3] * invl[3]);
        double m4 = fmax(-ds[4] * invs[4], -dl[4] * invl[4]);
        double m5 = fmax(-ds[5] * invs[5], -dl[5] * invl[5]);
        double m6 = fmax(-ds[6] * invs[6], -dl[6] * invl[6]);
        double m7 = fmax(-ds[7] * invs[7], -dl[7] * invl[7]);
        double m8 = fmax(-ds[8] * invs[8], -dl[8] * invl[8]);
        double MA = fmax(fmax(m0, m1), fmax(m2, m3));
        double MB = fmax(fmax(m4, m5), fmax(m6, m7));
        double M  = fmax(fmax(MA, MB), fmax(m8, 1e-300));
        // raw v_rcp_f64 safe: 0.99 factor gives 1% slack
        double alpha = 0.99 * fmin(1.0, __builtin_amdgcn_rcp(M));

        z[0] = fma(alpha, x0, z[0]);
        z[1] = fma(alpha, x1, z[1]);
        z[2] = fma(alpha, x2, z[2]);
        z[3] = fma(alpha, dz3, z[3]);
        z[4] = fma(alpha, dz4, z[4]);
        z[5] = fma(alpha, dz5, z[5]);
#pragma unroll
        for (int k = 0; k < 9; ++k) {
            s[k]   = fma(alpha, ds[k], s[k]);
            lam[k] = fma(alpha, dl[k], lam[k]);
        }
    }

    // ---- cost = 0.5 z'Qz + p'z + beta^2 ----
    double zQz = 4.001 * (z[0] * z[0] + z[1] * z[1]) - 8.0 * z[0] * z[1]
               + 0.001 * (z[2] * z[2] + z[3] * z[3] + z[4] * z[4] + z[5] * z[5]);
    double pz = p0 * z[0] + p1 * z[1] + p2 * z[2] + z[3] + z[4] + z[5];
    double cost = 0.5 * zQz + pz + beta * beta;

    out[i] = (float)cost;
}

extern "C" void kernel_launch(void* const* d_in, const int* in_sizes, int n_in,
                              void* d_out, int out_size, void* d_ws, size_t ws_size,
                              hipStream_t stream) {
    const float* vk = (const float*)d_in[0];
    const float* mu = (const float*)d_in[1];
    float* out = (float*)d_out;
    int B = in_sizes[0];
    int block = 64;
    int grid = (B + block - 1) / block;
    hipLaunchKernelGGL(qp_kernel, dim3(grid), dim3(block), 0, stream, vk, mu, out, B);
}

// Round 11
// 9.401 us; speedup vs baseline: 1.9128x; 1.2279x over previous
//
#include <hip/hip_runtime.h>
#include <math.h>

// B = 16384 independent QPs -> CLOSED FORM.
//
// Derivation (round 11): with D = z0 - z1, vu = v + 2, mu = input scalar:
//  * R = [-G | I3]: slack vars z3..z5 enter rows 6-8 with POSITIVE sign
//    (they tighten, never relax) and cost +1*z each  =>  z3=z4=z5=0.
//  * rows 6,7 (with z3=z4=0):  -D - z2 <= vu,  D - z2 <= -vu
//      =>  z2 >= |D + vu|; cost increasing in z2  =>  z2 = |D + vu|.
//  * 0.0005(z0^2+z1^2) at fixed D is minimized by min(z0,z1)=0
//      =>  z0*z1 = 0, z0^2+z1^2 = D^2; row 8 => z0+z1 = |D| <= mu.
//  * remaining 1-D convex problem on [-mu, mu]:
//      f(D) = 2.0005 D^2 + (3v+2) D + mu|D+vu| + 0.0005 (D+vu)^2
//    kink at D = -vu; branch derivative 4.002 D + 3.001 v + 2.002 +- mu;
//    pick branch root by kink-side validity, else kink; clamp to [-mu,mu].
//  * cost = 2.0005 D^2 + (3v+2) D + 0.0005 z2^2 + mu z2 + v^2.
//
// Validity of replacing the 20-iter IPM by the optimum: 12-iter Schur solver
// and 20-iter LU reference (different algorithms) agreed to the 3.05e-5
// output floor => both at the unique QP optimum ((z0,z1) Hessian block has
// eigenvalues {0.0005, 4.0005} > 0). The analytic optimum is that point.

__global__ __launch_bounds__(256) void qp_kernel(const float* __restrict__ vk,
                                                 const float* __restrict__ mup,
                                                 float* __restrict__ out, int B) {
    int i = blockIdx.x * blockDim.x + threadIdx.x;
    if (i >= B) return;

    const double v  = (double)vk[i];
    const double mu = (double)mup[0];
    const double vu = v + 2.0;

    const double lin = 3.001 * v + 2.002;
    const double inv4 = 1.0 / 4.002;            // compile-time constant

    // branch 1 (D + vu >= 0): root of 4.002 D + lin + mu
    double D1 = -(lin + mu) * inv4;
    double D;
    if (D1 + vu >= 0.0) {
        D = D1;
    } else {
        // branch 2 (D + vu <= 0): root of 4.002 D + lin - mu
        double D2 = -(lin - mu) * inv4;
        D = (D2 + vu <= 0.0) ? D2 : -vu;        // else kink is the minimum
    }
    // feasibility: |D| <= mu  (z0 + z1 = |D| <= h8 = mu)
    D = fmin(fmax(D, -mu), mu);

    const double z2 = fabs(D + vu);

    // cost = 2.0005 D^2 + (3v+2) D + 0.0005 z2^2 + mu z2 + v^2
    double cost = 2.0005 * D * D
                + (3.0 * v + 2.0) * D
                + 0.0005 * z2 * z2
                + mu * z2
                + v * v;

    out[i] = (float)cost;
}

extern "C" void kernel_launch(void* const* d_in, const int* in_sizes, int n_in,
                              void* d_out, int out_size, void* d_ws, size_t ws_size,
                              hipStream_t stream) {
    const float* vk = (const float*)d_in[0];
    const float* mu = (const float*)d_in[1];
    float* out = (float*)d_out;
    int B = in_sizes[0];
    int block = 256;
    int grid = (B + block - 1) / block;
    hipLaunchKernelGGL(qp_kernel, dim3(grid), dim3(block), 0, stream, vk, mu, out, B);
}

// Round 12
// 9.289 us; speedup vs baseline: 1.9360x; 1.0121x over previous
//
#include <hip/hip_runtime.h>
#include <math.h>

// B = 16384 independent QPs -> CLOSED FORM (derived round 11, verified:
// absmax 3.05e-5 = same floor as the 20-iter IPM reference).
//
//   D* = argmin_{|D|<=mu} 2.0005 D^2 + (3v+2) D + mu|D+vu| + 0.0005(D+vu)^2,
//   vu = v+2; piecewise-quadratic, kink at -vu:
//     branch roots D = -(3.001v + 2.002 +- mu)/4.002, select by kink-side
//     validity, else kink; clamp to [-mu, mu].
//   z2 = |D + vu|; cost = 2.0005 D^2 + (3v+2) D + 0.0005 z2^2 + mu z2 + v^2.
//
// ROUND 12: f32 (formula is well-conditioned; f32 err ~1e-6 << 3e-5 output
// floor) + float4 vectorization (4 elems/thread, 16B/lane loads). Kernel
// compute ~0.5us; measured 9.4us at round 11 => ~8us is launch/graph-replay
// overhead (harness floor). This round isolates that floor.

__global__ __launch_bounds__(256) void qp_kernel(const float4* __restrict__ vk4,
                                                 const float* __restrict__ mup,
                                                 float4* __restrict__ out4, int B4) {
    int i = blockIdx.x * blockDim.x + threadIdx.x;
    if (i >= B4) return;

    const float mu = mup[0];
    float4 v4 = vk4[i];
    float4 r;

    float* vin = (float*)&v4;
    float* ro  = (float*)&r;
#pragma unroll
    for (int k = 0; k < 4; ++k) {
        float v  = vin[k];
        float vu = v + 2.0f;
        float lin = 3.001f * v + 2.002f;

        float D1 = -(lin + mu) * (1.0f / 4.002f);
        float D2 = -(lin - mu) * (1.0f / 4.002f);
        // branch select: D1 valid if D1+vu>=0; else D2 if D2+vu<=0; else kink -vu
        float Dlo = (D2 + vu <= 0.0f) ? D2 : -vu;
        float D   = (D1 + vu >= 0.0f) ? D1 : Dlo;
        D = fminf(fmaxf(D, -mu), mu);

        float z2 = fabsf(D + vu);
        float cost = fmaf(fmaf(2.0005f, D, 3.0f * v + 2.0f), D,
                     fmaf(fmaf(0.0005f, z2, mu), z2, v * v));
        ro[k] = cost;
    }
    out4[i] = r;
}

extern "C" void kernel_launch(void* const* d_in, const int* in_sizes, int n_in,
                              void* d_out, int out_size, void* d_ws, size_t ws_size,
                              hipStream_t stream) {
    const float4* vk4 = (const float4*)d_in[0];
    const float*  mu  = (const float*)d_in[1];
    float4* out4 = (float4*)d_out;
    int B4 = in_sizes[0] / 4;          // B = 16384, divisible by 4
    int block = 256;
    int grid = (B4 + block - 1) / block;
    hipLaunchKernelGGL(qp_kernel, dim3(grid), dim3(block), 0, stream, vk4, mu, out4, B4);
}